// Round 1
// baseline (1624.862 us; speedup 1.0000x reference)
//
#include <hip/hip_runtime.h>
#include <cstddef>

#define B_    2
#define L_    2048
#define DM_   1024
#define NH_   16
#define DH_   64
#define TK_   32
#define SCALE_ 0.125f   // 1/sqrt(64)

// ---------------------------------------------------------------------------
// GEMM 128x128 tile, 8x8 microtile, fp32, C = A(MxK) @ W(KxN)
// ---------------------------------------------------------------------------
__global__ __launch_bounds__(256)
void gemm128(const float* __restrict__ A, const float* __restrict__ W,
             float* __restrict__ C, int N, int K) {
    __shared__ float As[16][136];   // [k][m], pad 8 -> row 544B = 34*16 (f4 aligned)
    __shared__ float Ws[16][136];   // [k][n]
    const int t  = threadIdx.x;
    const int bm = blockIdx.y << 7;
    const int bn = blockIdx.x << 7;
    const int tm = (t >> 4) << 3;
    const int tn = (t & 15) << 3;
    float acc[8][8] = {};
    const int am = t >> 1;            // 0..127
    const int ak = (t & 1) << 3;      // 0 or 8
    const int wk = t >> 4;            // 0..15
    const int wn = (t & 15) << 3;     // 0..120
    const float* Ap = A + (size_t)(bm + am) * K + ak;
    const float* Wp = W + (size_t)wk * N + bn + wn;
    for (int k0 = 0; k0 < K; k0 += 16) {
        float4 a0 = *(const float4*)(Ap + k0);
        float4 a1 = *(const float4*)(Ap + k0 + 4);
        float4 w0 = *(const float4*)(Wp + (size_t)k0 * N);
        float4 w1 = *(const float4*)(Wp + (size_t)k0 * N + 4);
        __syncthreads();   // protect previous iteration's LDS reads
        As[ak+0][am] = a0.x; As[ak+1][am] = a0.y; As[ak+2][am] = a0.z; As[ak+3][am] = a0.w;
        As[ak+4][am] = a1.x; As[ak+5][am] = a1.y; As[ak+6][am] = a1.z; As[ak+7][am] = a1.w;
        *(float4*)&Ws[wk][wn]     = w0;
        *(float4*)&Ws[wk][wn + 4] = w1;
        __syncthreads();
        #pragma unroll
        for (int kk = 0; kk < 16; ++kk) {
            float a_[8], w_[8];
            *(float4*)&a_[0] = *(const float4*)&As[kk][tm];
            *(float4*)&a_[4] = *(const float4*)&As[kk][tm + 4];
            *(float4*)&w_[0] = *(const float4*)&Ws[kk][tn];
            *(float4*)&w_[4] = *(const float4*)&Ws[kk][tn + 4];
            #pragma unroll
            for (int i = 0; i < 8; ++i)
                #pragma unroll
                for (int j = 0; j < 8; ++j)
                    acc[i][j] += a_[i] * w_[j];
        }
    }
    #pragma unroll
    for (int i = 0; i < 8; ++i) {
        float* Cp = C + (size_t)(bm + tm + i) * N + bn + tn;
        float4 o0 = {acc[i][0], acc[i][1], acc[i][2], acc[i][3]};
        float4 o1 = {acc[i][4], acc[i][5], acc[i][6], acc[i][7]};
        *(float4*)Cp       = o0;
        *(float4*)(Cp + 4) = o1;
    }
}

// ---------------------------------------------------------------------------
// GEMM 64x64 tile, 4x4 microtile (for the skinny kv projection, N=128)
// ---------------------------------------------------------------------------
__global__ __launch_bounds__(256)
void gemm64(const float* __restrict__ A, const float* __restrict__ W,
            float* __restrict__ C, int N, int K) {
    __shared__ float As[16][68];
    __shared__ float Ws[16][68];
    const int t  = threadIdx.x;
    const int bm = blockIdx.y << 6;
    const int bn = blockIdx.x << 6;
    const int tm = (t >> 4) << 2;
    const int tn = (t & 15) << 2;
    float acc[4][4] = {};
    const int am = t >> 2;           // 0..63
    const int ak = (t & 3) << 2;     // 0,4,8,12
    const int wk = t >> 4;           // 0..15
    const int wn = (t & 15) << 2;    // 0..60
    const float* Ap = A + (size_t)(bm + am) * K + ak;
    const float* Wp = W + (size_t)wk * N + bn + wn;
    for (int k0 = 0; k0 < K; k0 += 16) {
        float4 av = *(const float4*)(Ap + k0);
        float4 wv = *(const float4*)(Wp + (size_t)k0 * N);
        __syncthreads();
        As[ak+0][am] = av.x; As[ak+1][am] = av.y; As[ak+2][am] = av.z; As[ak+3][am] = av.w;
        *(float4*)&Ws[wk][wn] = wv;
        __syncthreads();
        #pragma unroll
        for (int kk = 0; kk < 16; ++kk) {
            float a_[4], w_[4];
            *(float4*)&a_[0] = *(const float4*)&As[kk][tm];
            *(float4*)&w_[0] = *(const float4*)&Ws[kk][tn];
            #pragma unroll
            for (int i = 0; i < 4; ++i)
                #pragma unroll
                for (int j = 0; j < 4; ++j)
                    acc[i][j] += a_[i] * w_[j];
        }
    }
    #pragma unroll
    for (int i = 0; i < 4; ++i) {
        float4 o = {acc[i][0], acc[i][1], acc[i][2], acc[i][3]};
        *(float4*)(C + (size_t)(bm + tm + i) * N + bn + tn) = o;
    }
}

// ---------------------------------------------------------------------------
// Column-wise (over sequence) L2 norm of kv -> k (row-major), kT, v
// grid: B_*128 blocks, block (b, c)
// ---------------------------------------------------------------------------
__global__ __launch_bounds__(256)
void normalize_kv(const float* __restrict__ kv, float* __restrict__ kn,
                  float* __restrict__ vn, float* __restrict__ knT) {
    const int bc = blockIdx.x;
    const int b  = bc >> 7;
    const int c  = bc & 127;
    const int t  = threadIdx.x;
    const float* base = kv + (size_t)b * L_ * 128 + c;
    float ss = 0.f;
    for (int l = t; l < L_; l += 256) {
        float x = base[(size_t)l * 128];
        ss += x * x;
    }
    #pragma unroll
    for (int off = 32; off; off >>= 1) ss += __shfl_xor(ss, off);
    __shared__ float red[4];
    if ((t & 63) == 0) red[t >> 6] = ss;
    __syncthreads();
    const float tot = red[0] + red[1] + red[2] + red[3];
    const float inv = 1.f / fmaxf(sqrtf(tot), 1e-12f);
    if (c < 64) {
        for (int l = t; l < L_; l += 256) {
            float x = base[(size_t)l * 128] * inv;
            kn[((size_t)b * L_ + l) * 64 + c]   = x;
            knT[((size_t)b * 64 + c) * L_ + l]  = x;
        }
    } else {
        for (int l = t; l < L_; l += 256) {
            float x = base[(size_t)l * 128] * inv;
            vn[((size_t)b * L_ + l) * 64 + (c - 64)] = x;
        }
    }
}

// ---------------------------------------------------------------------------
// Fused sims + softmax(local) + exact top-32 + retrieved.
// Block: 256 thr (4 waves), handles (b, h, 4 consecutive l). wave w owns row w
// for per-row phases; m-range is quartered across waves for sims / local acc.
// ---------------------------------------------------------------------------
__global__ __launch_bounds__(256)
void attn_topk(const float* __restrict__ q,    // (B, L, 1024)
               const float* __restrict__ kn,   // (B, L, 64)
               const float* __restrict__ knT,  // (B, 64, L)
               const float* __restrict__ vn,   // (B, L, 64)
               float* __restrict__ attn) {     // (B, L, 1024)
    const int l0   = blockIdx.x << 2;
    const int h    = blockIdx.y;
    const int b    = blockIdx.z;
    const int t    = threadIdx.x;
    const int w    = t >> 6;
    const int lane = t & 63;

    __shared__ float s_sims[4][L_];      // 32 KB: sims, then p in place
    __shared__ float s_q[4][DH_];        // 1 KB
    __shared__ float s_red[4][4][DH_];   // 4 KB: cross-wave local partials

    // ---- phase 0: stage q rows ----
    {
        const int r = t >> 6, d = t & 63;
        s_q[r][d] = q[((size_t)b * L_ + (l0 + r)) * DM_ + h * DH_ + d];
    }
    __syncthreads();

    // ---- phase 1: sims (wave w covers m in [512w, 512w+512), 4 m per lane) ----
    {
        const float* kTb = knT + (size_t)b * (64 * L_);
        #pragma unroll 1
        for (int jj = 0; jj < 2; ++jj) {
            const int mbase = (w << 9) + (jj << 8) + (lane << 2);
            float4 a0 = {0,0,0,0}, a1 = {0,0,0,0}, a2 = {0,0,0,0}, a3 = {0,0,0,0};
            const float* kp = kTb + mbase;
            #pragma unroll 8
            for (int d = 0; d < 64; ++d) {
                float4 k4 = *(const float4*)(kp + (size_t)d * L_);   // coalesced
                float q0 = s_q[0][d], q1 = s_q[1][d], q2 = s_q[2][d], q3 = s_q[3][d];
                a0.x += k4.x*q0; a0.y += k4.y*q0; a0.z += k4.z*q0; a0.w += k4.w*q0;
                a1.x += k4.x*q1; a1.y += k4.y*q1; a1.z += k4.z*q1; a1.w += k4.w*q1;
                a2.x += k4.x*q2; a2.y += k4.y*q2; a2.z += k4.z*q2; a2.w += k4.w*q2;
                a3.x += k4.x*q3; a3.y += k4.y*q3; a3.z += k4.z*q3; a3.w += k4.w*q3;
            }
            *(float4*)&s_sims[0][mbase] = a0;
            *(float4*)&s_sims[1][mbase] = a1;
            *(float4*)&s_sims[2][mbase] = a2;
            *(float4*)&s_sims[3][mbase] = a3;
        }
    }
    __syncthreads();

    // ---- phase 2: per-row (row r = w): exact top-32, then p=exp in place ----
    const int r = w;
    float smax_r = 0.f, denom_r;
    int   myci = 0;          // lane tsel (<32) holds tsel-th selected index
    float mycv = 0.f;        // ... and its sims value
    {
        // local argmax over this lane's 32 strided values
        float bv = -3e38f; int bi = lane;
        #pragma unroll
        for (int j = 0; j < 32; ++j) {
            int m = (j << 6) + lane;
            float x = s_sims[r][m];
            if (x > bv) { bv = x; bi = m; }
        }
        for (int tsel = 0; tsel < 32; ++tsel) {
            float cv = bv; int ci = bi;
            #pragma unroll
            for (int off = 32; off; off >>= 1) {  // butterfly argmax, ties -> low idx
                float ov = __shfl_xor(cv, off);
                int   oi = __shfl_xor(ci, off);
                if (ov > cv || (ov == cv && oi < ci)) { cv = ov; ci = oi; }
            }
            if (tsel == 0) smax_r = cv;            // global row max
            if (lane == tsel) { myci = ci; mycv = cv; }
            if ((ci & 63) == lane) {               // owner invalidates + rescans
                s_sims[r][ci] = -3e38f;
                bv = -3e38f; bi = lane;
                #pragma unroll
                for (int j = 0; j < 32; ++j) {
                    int m = (j << 6) + lane;
                    float x = s_sims[r][m];
                    if (x > bv) { bv = x; bi = m; }
                }
            }
        }
        // restore invalidated entries (cross-lane writes -> barrier below)
        if (lane < 32) s_sims[r][myci] = mycv;
    }
    __syncthreads();
    {
        float psum = 0.f;
        #pragma unroll 4
        for (int j = 0; j < 32; ++j) {
            int m = (j << 6) + lane;
            float p = __expf(SCALE_ * (s_sims[r][m] - smax_r));
            s_sims[r][m] = p;
            psum += p;
        }
        #pragma unroll
        for (int off = 32; off; off >>= 1) psum += __shfl_xor(psum, off);
        denom_r = psum;
    }
    __syncthreads();

    // ---- phase 3: local = p @ v  (wave w covers its m-quarter, all 4 rows) ----
    {
        float c0 = 0.f, c1 = 0.f, c2 = 0.f, c3 = 0.f;
        const float* vb_base = vn + (size_t)b * L_ * 64 + lane;
        for (int j4 = 0; j4 < 512; j4 += 4) {
            const int m = (w << 9) + j4;
            float4 p0 = *(const float4*)&s_sims[0][m];
            float4 p1 = *(const float4*)&s_sims[1][m];
            float4 p2 = *(const float4*)&s_sims[2][m];
            float4 p3 = *(const float4*)&s_sims[3][m];
            const float* vb = vb_base + (size_t)m * 64;
            float v0 = vb[0], v1 = vb[64], v2 = vb[128], v3 = vb[192];  // coalesced
            c0 += p0.x*v0 + p0.y*v1 + p0.z*v2 + p0.w*v3;
            c1 += p1.x*v0 + p1.y*v1 + p1.z*v2 + p1.w*v3;
            c2 += p2.x*v0 + p2.y*v1 + p2.z*v2 + p2.w*v3;
            c3 += p3.x*v0 + p3.y*v1 + p3.z*v2 + p3.w*v3;
        }
        s_red[w][0][lane] = c0;
        s_red[w][1][lane] = c1;
        s_red[w][2][lane] = c2;
        s_red[w][3][lane] = c3;
    }
    __syncthreads();

    // ---- phase 4: combine + retrieved (row r = w again), write out ----
    {
        float lsum = s_red[0][r][lane] + s_red[1][r][lane]
                   + s_red[2][r][lane] + s_red[3][r][lane];
        float localv = lsum / denom_r;
        float pt = 0.f;
        if (lane < 32) pt = __expf(SCALE_ * (mycv - smax_r));
        float rs = pt;
        #pragma unroll
        for (int off = 32; off; off >>= 1) rs += __shfl_xor(rs, off);
        float ret = 0.f;
        const float* knb = kn + (size_t)b * L_ * 64 + lane;
        #pragma unroll 4
        for (int tt = 0; tt < 32; ++tt) {
            int   m  = __shfl(myci, tt);
            float pv = __shfl(pt, tt);
            ret += pv * knb[(size_t)m * 64];   // coalesced gather of k rows
        }
        attn[((size_t)b * L_ + (l0 + r)) * DM_ + h * DH_ + lane] = localv + ret / rs;
    }
}

// ---------------------------------------------------------------------------
extern "C" void kernel_launch(void* const* d_in, const int* in_sizes, int n_in,
                              void* d_out, int out_size, void* d_ws, size_t ws_size,
                              hipStream_t stream) {
    const float* q_in     = (const float*)d_in[0];
    const float* kv_in    = (const float*)d_in[1];
    const float* w_q      = (const float*)d_in[2];
    const float* w_kv     = (const float*)d_in[3];
    const float* w_concat = (const float*)d_in[4];
    float* out = (float*)d_out;

    float* ws   = (float*)d_ws;
    float* q    = ws;                    // 4,194,304 f
    float* attn = ws + 4194304;          // 4,194,304 f
    float* kv   = attn;                  // aliased: kv dead before attn written
    float* kn   = ws + 8388608;          // 262,144 f
    float* vn   = kn + 262144;           // 262,144 f
    float* knT  = vn + 262144;           // 262,144 f   (total 36.7 MB)

    // q = q_in @ w_q   (4096x1024x1024)
    gemm128<<<dim3(DM_ / 128, (B_ * L_) / 128), 256, 0, stream>>>(q_in, w_q, q, DM_, DM_);
    // kv = kv_in @ w_kv (4096x1024x128) — skinny, use 64x64 tiles for block count
    gemm64<<<dim3(128 / 64, (B_ * L_) / 64), 256, 0, stream>>>(kv_in, w_kv, kv, 128, DM_);
    // column-norm split into kn / knT / vn
    normalize_kv<<<B_ * 128, 256, 0, stream>>>(kv, kn, vn, knT);
    // fused attention + top-k
    attn_topk<<<dim3(L_ / 4, NH_, B_), 256, 0, stream>>>(q, kn, knT, vn, attn);
    // out = attn @ w_concat
    gemm128<<<dim3(DM_ / 128, (B_ * L_) / 128), 256, 0, stream>>>(attn, w_concat, out, DM_, DM_);
}

// Round 2
// 1031.991 us; speedup vs baseline: 1.5745x; 1.5745x over previous
//
#include <hip/hip_runtime.h>
#include <cstddef>

#define B_    2
#define L_    2048
#define DM_   1024
#define NH_   16
#define DH_   64
#define TK_   32
#define SCALE_ 0.125f   // 1/sqrt(64)

typedef __bf16 bf16x8 __attribute__((ext_vector_type(8)));
typedef float  f32x4  __attribute__((ext_vector_type(4)));
typedef unsigned long long u64;

__device__ __forceinline__ unsigned flipf(float f) {
    unsigned u = __float_as_uint(f);
    return (u & 0x80000000u) ? ~u : (u | 0x80000000u);
}
__device__ __forceinline__ float unflipf(unsigned k) {
    unsigned u = (k & 0x80000000u) ? (k ^ 0x80000000u) : ~k;
    return __uint_as_float(u);
}
// ascending bitonic sort of one u64 per lane across 64 lanes
__device__ __forceinline__ u64 bsort64_asc(u64 v, int lane) {
    #pragma unroll
    for (int k = 2; k <= 64; k <<= 1) {
        #pragma unroll
        for (int j = k >> 1; j >= 1; j >>= 1) {
            u64 ov = __shfl_xor(v, j);
            bool keepMin = (((lane & k) == 0) == ((lane & j) == 0));
            bool less = v < ov;
            v = (keepMin == less) ? v : ov;
        }
    }
    return v;
}

// ---------------------------------------------------------------------------
// GEMM 128x128 tile, 8x8 microtile, fp32, C = A(MxK) @ W(KxN)
// ---------------------------------------------------------------------------
__global__ __launch_bounds__(256)
void gemm128(const float* __restrict__ A, const float* __restrict__ W,
             float* __restrict__ C, int N, int K) {
    __shared__ float As[16][136];
    __shared__ float Ws[16][136];
    const int t  = threadIdx.x;
    const int bm = blockIdx.y << 7;
    const int bn = blockIdx.x << 7;
    const int tm = (t >> 4) << 3;
    const int tn = (t & 15) << 3;
    float acc[8][8] = {};
    const int am = t >> 1;
    const int ak = (t & 1) << 3;
    const int wk = t >> 4;
    const int wn = (t & 15) << 3;
    const float* Ap = A + (size_t)(bm + am) * K + ak;
    const float* Wp = W + (size_t)wk * N + bn + wn;
    for (int k0 = 0; k0 < K; k0 += 16) {
        float4 a0 = *(const float4*)(Ap + k0);
        float4 a1 = *(const float4*)(Ap + k0 + 4);
        float4 w0 = *(const float4*)(Wp + (size_t)k0 * N);
        float4 w1 = *(const float4*)(Wp + (size_t)k0 * N + 4);
        __syncthreads();
        As[ak+0][am] = a0.x; As[ak+1][am] = a0.y; As[ak+2][am] = a0.z; As[ak+3][am] = a0.w;
        As[ak+4][am] = a1.x; As[ak+5][am] = a1.y; As[ak+6][am] = a1.z; As[ak+7][am] = a1.w;
        *(float4*)&Ws[wk][wn]     = w0;
        *(float4*)&Ws[wk][wn + 4] = w1;
        __syncthreads();
        #pragma unroll
        for (int kk = 0; kk < 16; ++kk) {
            float a_[8], w_[8];
            *(float4*)&a_[0] = *(const float4*)&As[kk][tm];
            *(float4*)&a_[4] = *(const float4*)&As[kk][tm + 4];
            *(float4*)&w_[0] = *(const float4*)&Ws[kk][tn];
            *(float4*)&w_[4] = *(const float4*)&Ws[kk][tn + 4];
            #pragma unroll
            for (int i = 0; i < 8; ++i)
                #pragma unroll
                for (int j = 0; j < 8; ++j)
                    acc[i][j] += a_[i] * w_[j];
        }
    }
    #pragma unroll
    for (int i = 0; i < 8; ++i) {
        float* Cp = C + (size_t)(bm + tm + i) * N + bn + tn;
        float4 o0 = {acc[i][0], acc[i][1], acc[i][2], acc[i][3]};
        float4 o1 = {acc[i][4], acc[i][5], acc[i][6], acc[i][7]};
        *(float4*)Cp       = o0;
        *(float4*)(Cp + 4) = o1;
    }
}

// ---------------------------------------------------------------------------
// GEMM 64x64 tile, 4x4 microtile (skinny kv projection, N=128)
// ---------------------------------------------------------------------------
__global__ __launch_bounds__(256)
void gemm64(const float* __restrict__ A, const float* __restrict__ W,
            float* __restrict__ C, int N, int K) {
    __shared__ float As[16][68];
    __shared__ float Ws[16][68];
    const int t  = threadIdx.x;
    const int bm = blockIdx.y << 6;
    const int bn = blockIdx.x << 6;
    const int tm = (t >> 4) << 2;
    const int tn = (t & 15) << 2;
    float acc[4][4] = {};
    const int am = t >> 2;
    const int ak = (t & 3) << 2;
    const int wk = t >> 4;
    const int wn = (t & 15) << 2;
    const float* Ap = A + (size_t)(bm + am) * K + ak;
    const float* Wp = W + (size_t)wk * N + bn + wn;
    for (int k0 = 0; k0 < K; k0 += 16) {
        float4 av = *(const float4*)(Ap + k0);
        float4 wv = *(const float4*)(Wp + (size_t)k0 * N);
        __syncthreads();
        As[ak+0][am] = av.x; As[ak+1][am] = av.y; As[ak+2][am] = av.z; As[ak+3][am] = av.w;
        *(float4*)&Ws[wk][wn] = wv;
        __syncthreads();
        #pragma unroll
        for (int kk = 0; kk < 16; ++kk) {
            float a_[4], w_[4];
            *(float4*)&a_[0] = *(const float4*)&As[kk][tm];
            *(float4*)&w_[0] = *(const float4*)&Ws[kk][tn];
            #pragma unroll
            for (int i = 0; i < 4; ++i)
                #pragma unroll
                for (int j = 0; j < 4; ++j)
                    acc[i][j] += a_[i] * w_[j];
        }
    }
    #pragma unroll
    for (int i = 0; i < 4; ++i) {
        float4 o = {acc[i][0], acc[i][1], acc[i][2], acc[i][3]};
        *(float4*)(C + (size_t)(bm + tm + i) * N + bn + tn) = o;
    }
}

// ---------------------------------------------------------------------------
// Column (sequence-axis) L2 norms of kv -> inv_norm[b][c]
// ---------------------------------------------------------------------------
__global__ __launch_bounds__(256)
void col_norms(const float* __restrict__ kv, float* __restrict__ invn) {
    const int bc = blockIdx.x;
    const int b  = bc >> 7;
    const int c  = bc & 127;
    const int t  = threadIdx.x;
    const float* base = kv + (size_t)b * L_ * 128 + c;
    float ss = 0.f;
    for (int l = t; l < L_; l += 256) {
        float x = base[(size_t)l * 128];
        ss += x * x;
    }
    #pragma unroll
    for (int off = 32; off; off >>= 1) ss += __shfl_xor(ss, off);
    __shared__ float red[4];
    if ((t & 63) == 0) red[t >> 6] = ss;
    __syncthreads();
    if (t == 0) {
        float tot = red[0] + red[1] + red[2] + red[3];
        invn[bc] = 1.f / fmaxf(sqrtf(tot), 1e-12f);
    }
}

// ---------------------------------------------------------------------------
// Scale kv by inv-norms and emit: kn fp32 (b,l,64), kh/kl bf16-split (b,l,64),
// vT bf16 transposed (b,64,l). Block: (l-tile of 64, b).
// ---------------------------------------------------------------------------
__global__ __launch_bounds__(256)
void scale_kv(const float* __restrict__ kv, const float* __restrict__ invn,
              float* __restrict__ kn, __bf16* __restrict__ kh,
              __bf16* __restrict__ kl, __bf16* __restrict__ vT) {
    const int b  = blockIdx.y;
    const int l0 = blockIdx.x << 6;
    const int t  = threadIdx.x;
    __shared__ float s_inv[128];
    __shared__ float s_vt[64][65];
    if (t < 128) s_inv[t] = invn[b * 128 + t];
    __syncthreads();
    #pragma unroll
    for (int rep = 0; rep < 8; ++rep) {
        int idx = (rep << 8) + t;          // 0..2047
        int li  = idx >> 5;                // 0..63
        int c4  = (idx & 31) << 2;         // 0..124
        float4 x = *(const float4*)(kv + ((size_t)(b * L_ + l0 + li)) * 128 + c4);
        x.x *= s_inv[c4]; x.y *= s_inv[c4+1]; x.z *= s_inv[c4+2]; x.w *= s_inv[c4+3];
        if (c4 < 64) {
            size_t o = ((size_t)(b * L_ + l0 + li)) * DH_ + c4;
            *(float4*)(kn + o) = x;
            __bf16 h0 = (__bf16)x.x, h1 = (__bf16)x.y, h2 = (__bf16)x.z, h3 = (__bf16)x.w;
            kh[o+0] = h0; kh[o+1] = h1; kh[o+2] = h2; kh[o+3] = h3;
            kl[o+0] = (__bf16)(x.x - (float)h0);
            kl[o+1] = (__bf16)(x.y - (float)h1);
            kl[o+2] = (__bf16)(x.z - (float)h2);
            kl[o+3] = (__bf16)(x.w - (float)h3);
        } else {
            int d = c4 - 64;
            s_vt[d+0][li] = x.x; s_vt[d+1][li] = x.y; s_vt[d+2][li] = x.z; s_vt[d+3][li] = x.w;
        }
    }
    __syncthreads();
    #pragma unroll
    for (int rep = 0; rep < 4; ++rep) {
        int idx = (rep << 8) + t;          // 0..1023
        int d   = idx >> 4;                // 0..63
        int j   = (idx & 15) << 2;         // 0..60
        size_t o = ((size_t)b * DH_ + d) * L_ + l0 + j;
        vT[o+0] = (__bf16)s_vt[d][j+0];
        vT[o+1] = (__bf16)s_vt[d][j+1];
        vT[o+2] = (__bf16)s_vt[d][j+2];
        vT[o+3] = (__bf16)s_vt[d][j+3];
    }
}

// ---------------------------------------------------------------------------
// Fused: sims via split-bf16 MFMA -> LDS; exact top-32 (threshold + fp32
// refine + bitonic); softmax-local via bf16 MFMA; retrieved; output.
// Block: 1024 thr (16 waves) handles (b, h, 16 q-rows).
// ---------------------------------------------------------------------------
__global__ __launch_bounds__(1024, 4)
void attn_topk(const float* __restrict__ q,    // (B, L, 1024) fp32
               const float* __restrict__ kn,   // (B, L, 64)  fp32
               const __bf16* __restrict__ kh,  // (B, L, 64)
               const __bf16* __restrict__ kl,  // (B, L, 64)
               const __bf16* __restrict__ vT,  // (B, 64, L)
               float* __restrict__ attn) {     // (B, L, 1024)
    const int l0   = blockIdx.x << 4;
    const int h    = blockIdx.y;
    const int b    = blockIdx.z;
    const int t    = threadIdx.x;
    const int w    = t >> 6;          // wave 0..15
    const int lane = t & 63;
    const int quad = lane >> 4;
    const int n15  = lane & 15;

    __shared__ float s_sims_raw[16 * 2052];          // 131,328 B (aliased later)
    __shared__ float s_qrow[16][64];                 // fp32 q rows for refine
    __shared__ u64   s_cand[16][128];                // candidate (key,idx)
    __shared__ float s_rowmax[16];
    __shared__ float s_dpart[16][16];                // per-wave denom partials

    float* s_part   = s_sims_raw;                    // [16][16][68] (aliased)
    float* s_local  = s_sims_raw + 18432;            // [16][64]
    float* s_denomF = s_sims_raw + 18432 + 1024;     // [16]

    // ---- phase 0: stage fp32 q rows ----
    s_qrow[w][lane] = q[((size_t)(b * L_ + l0 + w)) * DM_ + h * DH_ + lane];

    // ---- phase S: sims via split-bf16 MFMA (wave w -> m in [128w,128w+128)) ----
    {
        // A-fragments (on-the-fly split of fp32 q)
        bf16x8 qhf[2], qlf[2];
        const float* qp = q + ((size_t)(b * L_ + l0 + n15)) * DM_ + h * DH_ + (quad << 3);
        #pragma unroll
        for (int ks = 0; ks < 2; ++ks) {
            float4 x0 = *(const float4*)(qp + ks * 32);
            float4 x1 = *(const float4*)(qp + ks * 32 + 4);
            float xv[8] = {x0.x, x0.y, x0.z, x0.w, x1.x, x1.y, x1.z, x1.w};
            #pragma unroll
            for (int j = 0; j < 8; ++j) {
                __bf16 hh = (__bf16)xv[j];
                qhf[ks][j] = hh;
                qlf[ks][j] = (__bf16)(xv[j] - (float)hh);
            }
        }
        const __bf16* khb = kh + (size_t)b * L_ * DH_;
        const __bf16* klb = kl + (size_t)b * L_ * DH_;
        #pragma unroll 2
        for (int j = 0; j < 8; ++j) {
            int m0 = (w << 7) + (j << 4);
            const __bf16* kph = khb + (size_t)(m0 + n15) * DH_ + (quad << 3);
            const __bf16* kpl = klb + (size_t)(m0 + n15) * DH_ + (quad << 3);
            bf16x8 kh0 = *(const bf16x8*)(kph);
            bf16x8 kh1 = *(const bf16x8*)(kph + 32);
            bf16x8 kl0 = *(const bf16x8*)(kpl);
            bf16x8 kl1 = *(const bf16x8*)(kpl + 32);
            f32x4 acc = {0.f, 0.f, 0.f, 0.f};
            acc = __builtin_amdgcn_mfma_f32_16x16x32_bf16(qhf[0], kh0, acc, 0, 0, 0);
            acc = __builtin_amdgcn_mfma_f32_16x16x32_bf16(qhf[0], kl0, acc, 0, 0, 0);
            acc = __builtin_amdgcn_mfma_f32_16x16x32_bf16(qlf[0], kh0, acc, 0, 0, 0);
            acc = __builtin_amdgcn_mfma_f32_16x16x32_bf16(qhf[1], kh1, acc, 0, 0, 0);
            acc = __builtin_amdgcn_mfma_f32_16x16x32_bf16(qhf[1], kl1, acc, 0, 0, 0);
            acc = __builtin_amdgcn_mfma_f32_16x16x32_bf16(qlf[1], kh1, acc, 0, 0, 0);
            #pragma unroll
            for (int r = 0; r < 4; ++r)
                s_sims_raw[((quad << 2) + r) * 2052 + m0 + n15] = acc[r];
        }
    }
    __syncthreads();

    // ---- phase T: exact top-32 per row (wave w owns row w) ----
    int   myci = 0;
    float mycv = 0.f;
    {
        const int r = w;
        float* srow = s_sims_raw + r * 2052;
        // per-lane max over 32 strided values
        float bv = -3e38f;
        #pragma unroll
        for (int j = 0; j < 32; ++j) bv = fmaxf(bv, srow[(j << 6) + lane]);
        // sort the 64 lane-maxima (inverted keys, asc == desc values)
        unsigned mk = ~flipf(bv);
        #pragma unroll
        for (int k = 2; k <= 64; k <<= 1) {
            #pragma unroll
            for (int j = k >> 1; j >= 1; j >>= 1) {
                unsigned ov = __shfl_xor(mk, j);
                bool keepMin = (((lane & k) == 0) == ((lane & j) == 0));
                bool less = mk < ov;
                mk = (keepMin == less) ? mk : ov;
            }
        }
        float smaxf = unflipf(~__shfl(mk, 0));   // row max (approx sims)
        float thrf  = unflipf(~__shfl(mk, 31));  // m_(32): lower bound on T_true
        if (lane == 0) s_rowmax[r] = smaxf;
        // count candidates >= threshold
        int c = 0;
        #pragma unroll
        for (int j = 0; j < 32; ++j) c += (srow[(j << 6) + lane] >= thrf) ? 1 : 0;
        // exclusive prefix over lanes
        int incl = c;
        #pragma unroll
        for (int off = 1; off < 64; off <<= 1) {
            int nsum = __shfl_up(incl, off);
            if (lane >= off) incl += nsum;
        }
        int C = __shfl(incl, 63);
        int o = incl - c;
        if (C <= 128) {
            for (int j = 0; j < 32; ++j) {
                int m = (j << 6) + lane;
                float x = srow[m];
                if (x >= thrf) {
                    s_cand[r][o++] = ((u64)flipf(x) << 32) | (unsigned)(2047 - m);
                }
            }
        } else {
            // exact fallback (~never): iterative extraction of 48
            float bv2 = -3e38f; int bi2 = lane;
            for (int j = 0; j < 32; ++j) {
                int m = (j << 6) + lane; float x = srow[m];
                if (x > bv2) { bv2 = x; bi2 = m; }
            }
            int selci = 0; float selcv = 0.f;
            for (int tsel = 0; tsel < 48; ++tsel) {
                float cv = bv2; int ci = bi2;
                #pragma unroll
                for (int off2 = 32; off2; off2 >>= 1) {
                    float ov = __shfl_xor(cv, off2);
                    int   oi = __shfl_xor(ci, off2);
                    if (ov > cv || (ov == cv && oi < ci)) { cv = ov; ci = oi; }
                }
                if (lane == tsel) { selci = ci; selcv = cv; }
                if ((ci & 63) == lane) {
                    srow[ci] = -3e38f;
                    bv2 = -3e38f; bi2 = lane;
                    for (int j = 0; j < 32; ++j) {
                        int m = (j << 6) + lane; float x = srow[m];
                        if (x > bv2) { bv2 = x; bi2 = m; }
                    }
                }
            }
            if (lane < 48) {
                srow[selci] = selcv;
                s_cand[r][lane] = ((u64)flipf(selcv) << 32) | (unsigned)(2047 - selci);
            }
            C = 48;
        }
        // refine candidates with exact fp32 dot (selection = fp32-grade)
        const float* knb = kn + (size_t)b * L_ * DH_;
        for (int base = 0; base < C; base += 64) {
            int pidx = base + lane;
            bool act = pidx < C;
            u64 key = act ? s_cand[r][pidx] : 0ull;
            int m = act ? (2047 - (int)(unsigned)(key & 0xffffffffu)) : 0;
            const float* kr = knb + (size_t)m * DH_;
            float dot = 0.f;
            #pragma unroll
            for (int d4 = 0; d4 < 16; ++d4) {
                float4 kx = *(const float4*)(kr + (d4 << 2));
                float4 qx = *(const float4*)&s_qrow[r][d4 << 2];
                dot += kx.x * qx.x + kx.y * qx.y + kx.z * qx.z + kx.w * qx.w;
            }
            if (act) s_cand[r][pidx] = ((u64)flipf(dot) << 32) | (key & 0xffffffffu);
        }
        // final sort -> top-32 in lanes 0..31
        u64 v;
        if (C <= 64) {
            v = (lane < C) ? ~s_cand[r][lane] : ~0ull;
            v = bsort64_asc(v, lane);
        } else {
            u64 a  = ~s_cand[r][lane];
            u64 bq = (64 + lane < C) ? ~s_cand[r][64 + lane] : ~0ull;
            a  = bsort64_asc(a, lane);
            bq = bsort64_asc(bq, lane);
            u64 bb = __shfl(bq, 63 - lane);
            u64 s  = (lane < 32) ? a : bb;   // bitonic (asc then desc)
            #pragma unroll
            for (int j = 32; j >= 1; j >>= 1) {
                u64 ov = __shfl_xor(s, j);
                bool keepMin = ((lane & j) == 0);
                bool less = s < ov;
                s = (keepMin == less) ? s : ov;
            }
            v = s;
        }
        if (lane < 32) {
            u64 e = ~v;
            mycv = unflipf((unsigned)(e >> 32));
            myci = 2047 - (int)(unsigned)(e & 0xffffffffu);
        }
    }
    __syncthreads();

    // ---- phase L: local = softmax(sims) @ v via bf16 MFMA (wave w: its m-range) ----
    f32x4 accL[4] = {{0,0,0,0},{0,0,0,0},{0,0,0,0},{0,0,0,0}};
    {
        float mr = s_rowmax[n15];
        float dsum = 0.f;
        const __bf16* vtb = vT + (size_t)b * DH_ * L_;
        #pragma unroll
        for (int ks = 0; ks < 4; ++ks) {
            int mb = (w << 7) + (ks << 5) + (quad << 3);
            const float* sp = s_sims_raw + n15 * 2052 + mb;
            float4 s0 = *(const float4*)sp;
            float4 s1 = *(const float4*)(sp + 4);
            float p0 = __expf(SCALE_ * (s0.x - mr));
            float p1 = __expf(SCALE_ * (s0.y - mr));
            float p2 = __expf(SCALE_ * (s0.z - mr));
            float p3 = __expf(SCALE_ * (s0.w - mr));
            float p4 = __expf(SCALE_ * (s1.x - mr));
            float p5 = __expf(SCALE_ * (s1.y - mr));
            float p6 = __expf(SCALE_ * (s1.z - mr));
            float p7 = __expf(SCALE_ * (s1.w - mr));
            dsum += ((p0 + p1) + (p2 + p3)) + ((p4 + p5) + (p6 + p7));
            bf16x8 af;
            af[0] = (__bf16)p0; af[1] = (__bf16)p1; af[2] = (__bf16)p2; af[3] = (__bf16)p3;
            af[4] = (__bf16)p4; af[5] = (__bf16)p5; af[6] = (__bf16)p6; af[7] = (__bf16)p7;
            #pragma unroll
            for (int n = 0; n < 4; ++n) {
                bf16x8 bfv = *(const bf16x8*)(vtb + (size_t)((n << 4) + n15) * L_ + mb);
                accL[n] = __builtin_amdgcn_mfma_f32_16x16x32_bf16(af, bfv, accL[n], 0, 0, 0);
            }
        }
        dsum += __shfl_xor(dsum, 16);
        dsum += __shfl_xor(dsum, 32);
        if (lane < 16) s_dpart[w][lane] = dsum;
    }
    __syncthreads();   // all sims reads done; safe to alias
    {
        #pragma unroll
        for (int n = 0; n < 4; ++n)
            #pragma unroll
            for (int r = 0; r < 4; ++r)
                s_part[w * 1088 + ((quad << 2) + r) * 68 + (n << 4) + n15] = accL[n][r];
    }
    __syncthreads();

    // ---- phase R: reduce partials across 16 waves ----
    {
        int row = t >> 6, col = t & 63;
        float sum = 0.f;
        #pragma unroll
        for (int ww = 0; ww < 16; ++ww) sum += s_part[ww * 1088 + row * 68 + col];
        s_local[row * 64 + col] = sum;
        if (t < 16) {
            float dn = 0.f;
            #pragma unroll
            for (int ww = 0; ww < 16; ++ww) dn += s_dpart[ww][t];
            s_denomF[t] = dn;
        }
    }
    __syncthreads();

    // ---- phase V: retrieved (exact fp32) + combine + write ----
    {
        const int r = w;
        float lv = s_local[r * 64 + lane] / s_denomF[r];
        float maxv = __shfl(mycv, 0);
        float pt = (lane < 32) ? __expf(SCALE_ * (mycv - maxv)) : 0.f;
        float rs = pt;
        #pragma unroll
        for (int off = 32; off; off >>= 1) rs += __shfl_xor(rs, off);
        float ret = 0.f;
        const float* knb = kn + (size_t)b * L_ * DH_ + lane;
        #pragma unroll 4
        for (int tt = 0; tt < 32; ++tt) {
            int   m  = __shfl(myci, tt);
            float pv = __shfl(pt, tt);
            ret += pv * knb[(size_t)m * DH_];
        }
        attn[((size_t)(b * L_ + l0 + r)) * DM_ + h * DH_ + lane] = lv + ret / rs;
    }
}

// ---------------------------------------------------------------------------
extern "C" void kernel_launch(void* const* d_in, const int* in_sizes, int n_in,
                              void* d_out, int out_size, void* d_ws, size_t ws_size,
                              hipStream_t stream) {
    const float* q_in     = (const float*)d_in[0];
    const float* kv_in    = (const float*)d_in[1];
    const float* w_q      = (const float*)d_in[2];
    const float* w_kv     = (const float*)d_in[3];
    const float* w_concat = (const float*)d_in[4];
    float* out = (float*)d_out;

    float* ws   = (float*)d_ws;
    float* q    = ws;                    // 4,194,304 f
    float* attn = ws + 4194304;          // 4,194,304 f
    float* kv   = attn;                  // aliased: kv dead before attn written
    float* kn   = ws + 8388608;          // 262,144 f
    float* invn = ws + 8650752;          // 256 f
    __bf16* bfbase = (__bf16*)(ws + 8651008);
    __bf16* kh  = bfbase;                // 262,144 bf16
    __bf16* kl  = bfbase + 262144;       // 262,144 bf16
    __bf16* vT  = bfbase + 524288;       // 262,144 bf16  (b, 64, 2048)

    gemm128<<<dim3(DM_ / 128, (B_ * L_) / 128), 256, 0, stream>>>(q_in, w_q, q, DM_, DM_);
    gemm64<<<dim3(128 / 64, (B_ * L_) / 64), 256, 0, stream>>>(kv_in, w_kv, kv, 128, DM_);
    col_norms<<<B_ * 128, 256, 0, stream>>>(kv, invn);
    scale_kv<<<dim3(L_ / 64, B_), 256, 0, stream>>>(kv, invn, kn, kh, kl, vT);
    attn_topk<<<dim3(L_ / 16, NH_, B_), 1024, 0, stream>>>(q, kn, kh, kl, vT, attn);
    gemm128<<<dim3(DM_ / 128, (B_ * L_) / 128), 256, 0, stream>>>(attn, w_concat, out, DM_, DM_);
}